// Round 4
// baseline (79.228 us; speedup 1.0000x reference)
//
#include <hip/hip_runtime.h>
#include <stdint.h>

// Problem dims (fixed by reference)
#define D_DIM    768
#define K_STATES 128
#define M_ROWS   65536      // B*T = 256*256
#define BM       128        // rows per block = 4 waves x 32 rows
#define BK       32         // D-chunk per step
#define NSTEPS   (D_DIM / BK)   // 24

typedef __attribute__((ext_vector_type(8))) short bf16x8;
typedef __attribute__((ext_vector_type(4))) float f32x4;
typedef __attribute__((ext_vector_type(4))) int   i32x4;

__device__ __forceinline__ unsigned short f2bf(float f) {
    union { float f; unsigned u; } x; x.f = f;
    unsigned r = (x.u + 0x7FFFu + ((x.u >> 16) & 1u)) >> 16;   // RNE
    return (unsigned short)r;
}

// ---------------- prep: mw[k][d] = means*inv_var (bf16), c[k] = log_norm - 0.5*m2[k]
__global__ void __launch_bounds__(256) prep_kernel(
        const float* __restrict__ means, const float* __restrict__ var,
        unsigned short* __restrict__ mwbf, float* __restrict__ cvec) {
    const int k = blockIdx.x;
    const int t = threadIdx.x;
    float m2 = 0.f, ld = 0.f;
    for (int d = t; d < D_DIM; d += 256) {
        float v  = var[d];
        float iv = 1.0f / v;
        float m  = means[k * D_DIM + d];
        mwbf[k * D_DIM + d] = f2bf(m * iv);
        m2 += m * m * iv;
        ld += logf(v);
    }
#pragma unroll
    for (int off = 32; off > 0; off >>= 1) {
        m2 += __shfl_down(m2, off, 64);
        ld += __shfl_down(ld, off, 64);
    }
    __shared__ float rm[4], rl[4];
    const int wid = t >> 6;
    if ((t & 63) == 0) { rm[wid] = m2; rl[wid] = ld; }
    __syncthreads();
    if (t == 0) {
        float M2 = rm[0] + rm[1] + rm[2] + rm[3];
        float LD = rl[0] + rl[1] + rl[2] + rl[3];
        cvec[k] = -0.5f * ((float)D_DIM * 1.8378770664093453f + LD + M2);
    }
}

// ---------------- main: barrier-free, LDS-free K-loop.
// 4 waves/block, each wave owns 32 rows x 128 states exclusively.
// A: direct HBM->VGPR (each s element read once per block, fully coalesced).
// B: direct L2->VGPR from bf16 mwbf (196KB, L2-hot).
// Named ping-pong prefetch regs (static indexing only -- rule #20).
__global__ void __launch_bounds__(256, 2) dmv_main(
        const float* __restrict__ s, const unsigned short* __restrict__ mwbf,
        const float* __restrict__ var, const float* __restrict__ cvec,
        float* __restrict__ out) {
    __shared__ float ivs[D_DIM];   // 3 KB, written once in prologue

    const int t    = threadIdx.x;
    const int lane = t & 63;
    const int w    = t >> 6;
    const int r0   = lane & 15;        // M/N index within a 16x16 frag
    const int g    = (lane >> 4) * 8;  // K offset within BK
    const long rowBase = (long)blockIdx.x * BM + w * 32;

    const float*          pA = s    + (rowBase + r0) * D_DIM + g;
    const unsigned short* pB = mwbf + r0 * D_DIM + g;

    f32x4 acc[2][8];
#pragma unroll
    for (int i = 0; i < 2; ++i)
#pragma unroll
        for (int j = 0; j < 8; ++j) acc[i][j] = f32x4{0.f, 0.f, 0.f, 0.f};

    // ping-pong raw prefetch registers (all statically indexed)
    f32x4 a0_[2][2], a1_[2][2];
    i32x4 b0_[8], b1_[8];

#define LOADA(DST, ST) do {                                                    \
    _Pragma("unroll")                                                          \
    for (int i = 0; i < 2; ++i) {                                              \
        const float* p = pA + (long)i * 16 * D_DIM + (ST) * BK;                \
        DST[i][0] = *(const f32x4*)(p);                                        \
        DST[i][1] = *(const f32x4*)(p + 4);                                    \
    } } while (0)

#define LOADB(DST, ST) do {                                                    \
    _Pragma("unroll")                                                          \
    for (int j = 0; j < 8; ++j)                                                \
        DST[j] = *(const i32x4*)(pB + (long)j * 16 * D_DIM + (ST) * BK);       \
    } while (0)

    // issue step-0/1 loads before touching LDS (no dependence on barrier)
    LOADA(a0_, 0); LOADB(b0_, 0);
    LOADA(a1_, 1); LOADB(b1_, 1);

    for (int d = t; d < D_DIM; d += 256) ivs[d] = 1.0f / var[d];
    __syncthreads();               // the only block barrier

    float s2acc[2] = {0.f, 0.f};

#define STEP(ARAW, BRAW, K0) do {                                              \
    f32x4 iv0 = *(const f32x4*)&ivs[(K0) + g];                                 \
    f32x4 iv1 = *(const f32x4*)&ivs[(K0) + g + 4];                             \
    bf16x8 af[2];                                                              \
    _Pragma("unroll")                                                          \
    for (int i = 0; i < 2; ++i) {                                              \
        f32x4 v0 = ARAW[i][0], v1 = ARAW[i][1];                                \
        s2acc[i] += v0[0]*v0[0]*iv0[0] + v0[1]*v0[1]*iv0[1]                    \
                  + v0[2]*v0[2]*iv0[2] + v0[3]*v0[3]*iv0[3]                    \
                  + v1[0]*v1[0]*iv1[0] + v1[1]*v1[1]*iv1[1]                    \
                  + v1[2]*v1[2]*iv1[2] + v1[3]*v1[3]*iv1[3];                   \
        union { bf16x8 h; unsigned u[4]; } pk;                                 \
        pk.u[0] = (unsigned)f2bf(v0[0]) | ((unsigned)f2bf(v0[1]) << 16);       \
        pk.u[1] = (unsigned)f2bf(v0[2]) | ((unsigned)f2bf(v0[3]) << 16);       \
        pk.u[2] = (unsigned)f2bf(v1[0]) | ((unsigned)f2bf(v1[1]) << 16);       \
        pk.u[3] = (unsigned)f2bf(v1[2]) | ((unsigned)f2bf(v1[3]) << 16);       \
        af[i] = pk.h;                                                          \
    }                                                                          \
    _Pragma("unroll")                                                          \
    for (int j = 0; j < 8; ++j) {                                              \
        union { i32x4 i; bf16x8 h; } bb; bb.i = BRAW[j];                       \
        acc[0][j] = __builtin_amdgcn_mfma_f32_16x16x32_bf16(af[0], bb.h,       \
                                                            acc[0][j], 0,0,0);\
        acc[1][j] = __builtin_amdgcn_mfma_f32_16x16x32_bf16(af[1], bb.h,       \
                                                            acc[1][j], 0,0,0);\
    } } while (0)

    for (int st = 0; st < NSTEPS; st += 2) {
        STEP(a0_, b0_, st * BK);
        if (st + 2 < NSTEPS) { LOADA(a0_, st + 2); LOADB(b0_, st + 2); }
        STEP(a1_, b1_, (st + 1) * BK);
        if (st + 3 < NSTEPS) { LOADA(a1_, st + 3); LOADB(b1_, st + 3); }
    }

    // s2: sum across the 4 k-groups (lanes l, l+16, l+32, l+48 share a row)
#pragma unroll
    for (int i = 0; i < 2; ++i) {
        s2acc[i] += __shfl_xor(s2acc[i], 16, 64);
        s2acc[i] += __shfl_xor(s2acc[i], 32, 64);
    }

    // per-state constant: col j*16 + r0  (cvec is L2-hot)
    float cj[8];
#pragma unroll
    for (int j = 0; j < 8; ++j) cj[j] = cvec[j * 16 + r0];

    // epilogue: C/D layout col = lane&15, row = (lane>>4)*4 + reg [m89/m91]
    const int q = lane >> 4;
#pragma unroll
    for (int i = 0; i < 2; ++i) {
#pragma unroll
        for (int r = 0; r < 4; ++r) {
            float s2v = __shfl(s2acc[i], q * 4 + r, 64);   // holder: lane q*4+r
            const long row = rowBase + i * 16 + q * 4 + r;
            float* po = out + row * K_STATES + r0;
            const float base = -0.5f * s2v;
#pragma unroll
            for (int j = 0; j < 8; ++j)
                __builtin_nontemporal_store(acc[i][j][r] + cj[j] + base, po + j * 16);
        }
    }
#undef LOADA
#undef LOADB
#undef STEP
}

extern "C" void kernel_launch(void* const* d_in, const int* in_sizes, int n_in,
                              void* d_out, int out_size, void* d_ws, size_t ws_size,
                              hipStream_t stream) {
    const float* s     = (const float*)d_in[0];
    const float* means = (const float*)d_in[1];
    const float* var   = (const float*)d_in[2];
    float* out = (float*)d_out;

    unsigned short* mwbf = (unsigned short*)d_ws;
    float* cvec = (float*)((char*)d_ws + (size_t)K_STATES * D_DIM * sizeof(unsigned short));

    prep_kernel<<<K_STATES, 256, 0, stream>>>(means, var, mwbf, cvec);
    dmv_main<<<M_ROWS / BM, 256, 0, stream>>>(s, mwbf, var, cvec, out);
}

// Round 5
// 46.024 us; speedup vs baseline: 1.7215x; 1.7215x over previous
//
#include <hip/hip_runtime.h>
#include <hip/hip_bf16.h>
#include <stdint.h>

// Problem dims (fixed by reference)
#define D_DIM    768
#define K_STATES 128
#define M_ROWS   65536      // B*T = 256*256
#define BM       64         // rows per block
#define BK       32         // D-chunk per K-step
#define NSTEPS   (D_DIM / BK)   // 24
#define LDSTRIDE 40         // bf16 elems per LDS row: 80B, 16B-aligned, 2-way-max banks

typedef __attribute__((ext_vector_type(8))) short bf16x8;
typedef __attribute__((ext_vector_type(4))) float f32x4;
typedef __attribute__((ext_vector_type(4))) int   i32x4;

__device__ __forceinline__ unsigned short f2bf(float f) {
    union { float f; unsigned u; } x; x.f = f;
    unsigned r = (x.u + 0x7FFFu + ((x.u >> 16) & 1u)) >> 16;   // RNE
    return (unsigned short)r;
}

// ---------------- prep: mw[k][d] = means*inv_var (bf16), c[k] = log_norm - 0.5*m2[k]
__global__ void __launch_bounds__(256) prep_kernel(
        const float* __restrict__ means, const float* __restrict__ var,
        unsigned short* __restrict__ mwbf, float* __restrict__ cvec) {
    const int k = blockIdx.x;
    const int t = threadIdx.x;
    float m2 = 0.f, ld = 0.f;
    for (int d = t; d < D_DIM; d += 256) {
        float v  = var[d];
        float iv = 1.0f / v;
        float m  = means[k * D_DIM + d];
        mwbf[k * D_DIM + d] = f2bf(m * iv);
        m2 += m * m * iv;
        ld += logf(v);
    }
#pragma unroll
    for (int off = 32; off > 0; off >>= 1) {
        m2 += __shfl_down(m2, off, 64);
        ld += __shfl_down(ld, off, 64);
    }
    __shared__ float rm[4], rl[4];
    const int wid = t >> 6;
    if ((t & 63) == 0) { rm[wid] = m2; rl[wid] = ld; }
    __syncthreads();
    if (t == 0) {
        float M2 = rm[0] + rm[1] + rm[2] + rm[3];
        float LD = rl[0] + rl[1] + rl[2] + rl[3];
        cvec[k] = -0.5f * ((float)D_DIM * 1.8378770664093453f + LD + M2);
    }
}

// ---------------- main: R1 skeleton + depth-2 reg prefetch + hw cvt_pk
// Block: 64 rows x 128 states, 4 waves each 32x64 (acc[2][4]), grid = 1024,
// 4 blocks/CU. LDS double-buffer, ONE barrier per K-step; global loads are
// issued 2 steps before consumption and stay in flight across barriers.
__global__ void __launch_bounds__(256, 4) dmv_main(
        const float* __restrict__ s, const unsigned short* __restrict__ mwbf,
        const float* __restrict__ var, const float* __restrict__ cvec,
        float* __restrict__ out) {
    __shared__ unsigned short As[2][BM * LDSTRIDE];        // 2 x 5.0 KB
    __shared__ unsigned short Bs[2][K_STATES * LDSTRIDE];  // 2 x 10.0 KB
    __shared__ float ivs[D_DIM];                           // 3 KB
    __shared__ float part[BM][8];
    __shared__ float s2row[BM];
    __shared__ float cs[K_STATES];

    const int t    = threadIdx.x;
    const int lane = t & 63;
    const int w    = t >> 6;
    const int wr   = w >> 1;
    const int wc   = w & 1;
    const long rowBase = (long)blockIdx.x * BM;

    for (int d = t; d < D_DIM; d += 256) ivs[d] = 1.0f / var[d];
    if (t < K_STATES) cs[t] = cvec[t];

    // staging geometry per K-step:
    // A (64x32 f32): row = j*32 + (t>>3), cols (t&7)*4 .. +3   (2 x f32x4/thread)
    // B (128x32 bf16): row = j*64 + (t>>2), cols (t&3)*8 .. +7 (2 x i32x4/thread)
    const int arow0 = t >> 3;
    const int acol  = (t & 7) * 4;
    const int brow0 = t >> 2;
    const int bcol  = (t & 3) * 8;

    const float*          sA = s    + (rowBase + arow0) * D_DIM + acol;
    const unsigned short* sB = mwbf + brow0 * D_DIM + bcol;

    f32x4 a0_[2], a1_[2];     // two named prefetch sets (rule #20: static only)
    i32x4 b0_[2], b1_[2];
    float s2acc[2] = {0.f, 0.f};

    f32x4 acc[2][4];
#pragma unroll
    for (int i = 0; i < 2; ++i)
#pragma unroll
        for (int j = 0; j < 4; ++j) acc[i][j] = f32x4{0.f, 0.f, 0.f, 0.f};

#define LOADP(AP, BP, ST) do {                                                 \
    AP[0] = *(const f32x4*)(sA + (ST) * BK);                                   \
    AP[1] = *(const f32x4*)(sA + (long)32 * D_DIM + (ST) * BK);                \
    BP[0] = *(const i32x4*)(sB + (ST) * BK);                                   \
    BP[1] = *(const i32x4*)(sB + (long)64 * D_DIM + (ST) * BK);                \
} while (0)

#define STAGE(BUF, AP, BP, K0) do {                                            \
    f32x4 ivv = *reinterpret_cast<const f32x4*>(&ivs[(K0) + acol]);            \
    _Pragma("unroll")                                                          \
    for (int j = 0; j < 2; ++j) {                                              \
        const int row = j * 32 + arow0;                                        \
        f32x4 v = AP[j];                                                       \
        s2acc[j] += v[0]*v[0]*ivv[0] + v[1]*v[1]*ivv[1]                        \
                  + v[2]*v[2]*ivv[2] + v[3]*v[3]*ivv[3];                       \
        __hip_bfloat162 p0 = __float22bfloat162_rn(make_float2(v[0], v[1]));   \
        __hip_bfloat162 p1 = __float22bfloat162_rn(make_float2(v[2], v[3]));   \
        union { uint2 u2; __hip_bfloat162 h[2]; } pk;                          \
        pk.h[0] = p0; pk.h[1] = p1;                                            \
        *reinterpret_cast<uint2*>(&As[BUF][row * LDSTRIDE + acol]) = pk.u2;    \
    }                                                                          \
    _Pragma("unroll")                                                          \
    for (int j = 0; j < 2; ++j)                                                \
        *reinterpret_cast<i32x4*>(&Bs[BUF][(j * 64 + brow0) * LDSTRIDE + bcol])\
            = BP[j];                                                           \
} while (0)

    const int g  = (lane >> 4) * 8;
    const int rA = wr * 32 + (lane & 15);
    const int rB = wc * 64 + (lane & 15);

#define COMPUTE(BUF) do {                                                      \
    const unsigned short* Ab = &As[BUF][0];                                    \
    const unsigned short* Bb = &Bs[BUF][0];                                    \
    bf16x8 afrag[2], bfrag[4];                                                 \
    _Pragma("unroll")                                                          \
    for (int i = 0; i < 2; ++i)                                                \
        afrag[i] = *(const bf16x8*)(Ab + (rA + i * 16) * LDSTRIDE + g);        \
    _Pragma("unroll")                                                          \
    for (int j = 0; j < 4; ++j)                                                \
        bfrag[j] = *(const bf16x8*)(Bb + (rB + j * 16) * LDSTRIDE + g);        \
    _Pragma("unroll")                                                          \
    for (int i = 0; i < 2; ++i)                                                \
        _Pragma("unroll")                                                      \
        for (int j = 0; j < 4; ++j)                                            \
            acc[i][j] = __builtin_amdgcn_mfma_f32_16x16x32_bf16(               \
                            afrag[i], bfrag[j], acc[i][j], 0, 0, 0);           \
} while (0)

    // prologue: establish invariant for st=0:
    //   buf0 staged(step0); P1 holds step1; P0 holds step2
    LOADP(a0_, b0_, 0);
    LOADP(a1_, b1_, 1);
    __syncthreads();               // ivs/cs ready
    STAGE(0, a0_, b0_, 0);
    LOADP(a0_, b0_, 2);
    __syncthreads();               // buf0 visible

    for (int st = 0; st < NSTEPS; st += 2) {
        COMPUTE(0);                                  // step st
        STAGE(1, a1_, b1_, (st + 1) * BK);           // step st+1 (always valid)
        if (st + 3 < NSTEPS) LOADP(a1_, b1_, st + 3);
        __syncthreads();

        COMPUTE(1);                                  // step st+1
        if (st + 2 < NSTEPS) STAGE(0, a0_, b0_, (st + 2) * BK);
        if (st + 4 < NSTEPS) LOADP(a0_, b0_, st + 4);
        __syncthreads();
    }

    // s2 reduction: thread owns rows {j*32 + (t>>3)}, col-slot t&7
#pragma unroll
    for (int j = 0; j < 2; ++j) part[j * 32 + arow0][t & 7] = s2acc[j];
    __syncthreads();
    if (t < BM) {
        float v = 0.f;
#pragma unroll
        for (int sl = 0; sl < 8; ++sl) v += part[t][sl];
        s2row[t] = v;
    }
    __syncthreads();

    // epilogue: C/D layout col = lane&15, row = (lane>>4)*4 + reg [m89/m91]
    const int colBase = wc * 64 + (lane & 15);
#pragma unroll
    for (int i = 0; i < 2; ++i) {
        const int rl0 = wr * 32 + i * 16 + (lane >> 4) * 4;
#pragma unroll
        for (int j = 0; j < 4; ++j) {
            const int col = colBase + j * 16;
            const float cj = cs[col];
#pragma unroll
            for (int r = 0; r < 4; ++r) {
                const int rl = rl0 + r;
                out[(rowBase + rl) * K_STATES + col] = acc[i][j][r] + cj - 0.5f * s2row[rl];
            }
        }
    }
#undef LOADP
#undef STAGE
#undef COMPUTE
}

extern "C" void kernel_launch(void* const* d_in, const int* in_sizes, int n_in,
                              void* d_out, int out_size, void* d_ws, size_t ws_size,
                              hipStream_t stream) {
    const float* s     = (const float*)d_in[0];
    const float* means = (const float*)d_in[1];
    const float* var   = (const float*)d_in[2];
    float* out = (float*)d_out;

    unsigned short* mwbf = (unsigned short*)d_ws;
    float* cvec = (float*)((char*)d_ws + (size_t)K_STATES * D_DIM * sizeof(unsigned short));

    prep_kernel<<<K_STATES, 256, 0, stream>>>(means, var, mwbf, cvec);
    dmv_main<<<M_ROWS / BM, 256, 0, stream>>>(s, mwbf, var, cvec, out);
}